// Round 15
// baseline (187.627 us; speedup 1.0000x reference)
//
#include <hip/hip_runtime.h>
#include <stdint.h>

#define NB 4096   // query rows
#define NM 8192   // memory rows
#define ND 1024   // feature dim

typedef __attribute__((ext_vector_type(8))) short bf16x8;
typedef __attribute__((ext_vector_type(4))) float f32x4;
typedef __attribute__((ext_vector_type(8))) unsigned short u16x8;
typedef __attribute__((ext_vector_type(4))) int i32x4;
typedef __attribute__((ext_vector_type(8))) int i32x8;

#define SCONE 0x7F7F7F7F   // four e8m0 scales = 2^0 (opsel-proof)

static __device__ __forceinline__ unsigned short f2bf(float f) {
  union { float f; uint32_t u; } v; v.f = f;
  uint32_t u = v.u;
  u += 0x7fffu + ((u >> 16) & 1u);   // RNE
  return (unsigned short)(u >> 16);
}
static __device__ __forceinline__ float bf2f(unsigned short b) {
  union { uint32_t u; float f; } v; v.u = ((uint32_t)b) << 16; return v.f;
}
// fp32 -> OCP e4m3fn, RNE, saturating (manual; no header dependency)
static __device__ __forceinline__ uint8_t f2fp8(float f) {
  union { float f; uint32_t u; } v; v.f = f;
  const uint8_t s = (uint8_t)((v.u >> 31) << 7);
  const float a = fabsf(f);
  if (a >= 448.f) return s | 0x7E;
  if (a < 0.0009765625f) return s;            // < 2^-10 -> 0
  const uint32_t u = v.u & 0x7FFFFFFFu;
  const int e = (int)(u >> 23) - 127;
  if (e < -6) {                                // subnormal: m * 2^-9
    int m = (int)rintf(a * 512.f);
    if (m >= 8) return s | 0x08;
    return s | (uint8_t)m;
  }
  const uint32_t r = u + 0x7FFFFu + ((u >> 20) & 1u);  // RNE to 3-bit mant
  const int e2 = (int)(r >> 23) - 127;
  if (e2 > 8) return s | 0x7E;
  return s | (uint8_t)((e2 + 7) << 3) | (uint8_t)((r >> 20) & 7u);
}

static __device__ __forceinline__ void gload_lds16(const void* g, void* l) {
  __builtin_amdgcn_global_load_lds(
      (__attribute__((address_space(1))) void*)g,
      (__attribute__((address_space(3))) void*)l, 16, 0, 0);
}

#define BAR()   __builtin_amdgcn_s_barrier()
#define LGKM0() asm volatile("s_waitcnt lgkmcnt(0)" ::: "memory")
#define VMC8()  asm volatile("s_waitcnt vmcnt(8)" ::: "memory")
#define VMC2()  asm volatile("s_waitcnt vmcnt(2)" ::: "memory")
#define VMC0()  asm volatile("s_waitcnt vmcnt(0)" ::: "memory")

// ---- normalize mem rows -> bf16 (memn) + fp8 (memn8) -----------------------
__global__ void nrm_m8(const float* __restrict__ x, unsigned short* __restrict__ ob,
                       uint8_t* __restrict__ o8) {
  const int row = blockIdx.x, t = threadIdx.x;
  const float4 v = ((const float4*)(x + (size_t)row * ND))[t];
  float ss = v.x * v.x + v.y * v.y + v.z * v.z + v.w * v.w;
  #pragma unroll
  for (int o = 32; o > 0; o >>= 1) ss += __shfl_xor(ss, o);
  __shared__ float red[4];
  if ((t & 63) == 0) red[t >> 6] = ss;
  __syncthreads();
  ss = (red[0] + red[1]) + (red[2] + red[3]);
  const float sc = 1.0f / fmaxf(sqrtf(ss), 1e-12f);
  ushort4 o4;
  o4.x = f2bf(v.x * sc); o4.y = f2bf(v.y * sc);
  o4.z = f2bf(v.z * sc); o4.w = f2bf(v.w * sc);
  ((ushort4*)(ob + (size_t)row * ND))[t] = o4;
  uchar4 c4;
  c4.x = f2fp8(v.x * sc); c4.y = f2fp8(v.y * sc);
  c4.z = f2fp8(v.z * sc); c4.w = f2fp8(v.w * sc);
  ((uchar4*)(o8 + (size_t)row * ND))[t] = c4;
}

// ---- normalize q rows -> fp8 only ------------------------------------------
__global__ void nrm_q8(const float* __restrict__ x, uint8_t* __restrict__ o8) {
  const int row = blockIdx.x, t = threadIdx.x;
  const float4 v = ((const float4*)(x + (size_t)row * ND))[t];
  float ss = v.x * v.x + v.y * v.y + v.z * v.z + v.w * v.w;
  #pragma unroll
  for (int o = 32; o > 0; o >>= 1) ss += __shfl_xor(ss, o);
  __shared__ float red[4];
  if ((t & 63) == 0) red[t >> 6] = ss;
  __syncthreads();
  ss = (red[0] + red[1]) + (red[2] + red[3]);
  const float sc = 1.0f / fmaxf(sqrtf(ss), 1e-12f);
  uchar4 c4;
  c4.x = f2fp8(v.x * sc); c4.y = f2fp8(v.y * sc);
  c4.z = f2fp8(v.z * sc); c4.w = f2fp8(v.w * sc);
  ((uchar4*)(o8 + (size_t)row * ND))[t] = c4;
}

// ---- transpose memn [8192x1024] bf16 -> memt [1024x8192] bf16 --------------
__global__ void tr_kernel(const unsigned short* __restrict__ memn, unsigned short* __restrict__ memt) {
  __shared__ unsigned short Ts[64][66];
  const int t = threadIdx.x;
  const int d0 = blockIdx.x * 64, m0 = blockIdx.y * 64;
  #pragma unroll
  for (int r = 0; r < 2; ++r) {
    const int lrow = r * 32 + (t >> 3);
    const int lcol = (t & 7) * 8;
    u16x8 v = *(const u16x8*)(memn + (size_t)(m0 + lrow) * ND + d0 + lcol);
    #pragma unroll
    for (int j = 0; j < 8; ++j) Ts[lcol + j][lrow] = v[j];
  }
  __syncthreads();
  #pragma unroll
  for (int r = 0; r < 2; ++r) {
    const int orow = r * 32 + (t >> 3);
    const int ocol = (t & 7) * 8;
    u16x8 o;
    #pragma unroll
    for (int j = 0; j < 8; ++j) o[j] = Ts[orow][ocol + j];
    *(u16x8*)(memt + (size_t)(d0 + orow) * NM + m0 + ocol) = o;
  }
}

// ====== GEMM1: 256x256, MX-fp8 K=128 MFMA, r10 ring schedule ================
__global__ __launch_bounds__(512, 2) void gemm4x(
    const uint8_t* __restrict__ A, const uint8_t* __restrict__ B,
    unsigned short* __restrict__ E, float* __restrict__ psum,
    int ld, int ldc, int mt, int kchunk)
{
  extern __shared__ char smem[];   // [buf][A 32K | B 32K] x2 = 128 KiB
  const int t = threadIdx.x;
  const int w = t >> 6, l = t & 63;
  const int wr = w >> 2, wc = w & 3;
  const int nwg = gridDim.x, cpx = nwg >> 3;
  const int id = (blockIdx.x & 7) * cpx + (blockIdx.x >> 3);  // XCD swizzle
  const int brow = id % mt, bcol = id / mt;
  const int nt = kchunk >> 7;          // K-tiles of 128 (8; even)

  const int srow = l >> 3;                       // staging row-in-8-group
  const int scol = ((l & 7) ^ srow) << 4;        // pre-swizzled global col (B)
  const int lr = l & 15, lhi = l >> 4;
  const int swz = (l & 7) << 4;
  const int cb0 = (lhi * 32) ^ swz;              // frag lo 16B
  const int cb1 = (lhi * 32 + 16) ^ swz;         // frag hi 16B
  const int aoffr = (wr * 16 + lr) * 128;        // + m*4096
  const int boffr = (wc * 16 + lr) * 128;        // + nf*8192

  const uint8_t* Ab = A + (size_t)(brow * 256 + w * 8 + srow) * ld + scol;
  const uint8_t* Bb = B + (size_t)(bcol * 256 + w * 8 + srow) * ld + scol;

  auto stageA = [&](int p, int h, int tau) {     // one half-region = 2 gloads
    const int kt = (tau < nt ? tau : nt - 1) << 7;
    const uint8_t* g = Ab + (size_t)(h * 128) * ld + kt;
    char* d = smem + p * 65536 + h * 16384 + w * 1024;
    gload_lds16(g, d);
    gload_lds16(g + (size_t)64 * ld, d + 8192);
  };
  auto stageB = [&](int p, int h, int tau) {
    const int kt = (tau < nt ? tau : nt - 1) << 7;
    const uint8_t* g = Bb + (size_t)(h * 128) * ld + kt;
    char* d = smem + p * 65536 + 32768 + h * 16384 + w * 1024;
    gload_lds16(g, d);
    gload_lds16(g + (size_t)64 * ld, d + 8192);
  };
  auto ldA4 = [&](int p, int m, int c) -> i32x4 {
    return *(const i32x4*)(smem + p * 65536 + m * 4096 + aoffr + (c ? cb1 : cb0));
  };
  auto ldB4 = [&](int p, int nf, int c) -> i32x4 {
    return *(const i32x4*)(smem + p * 65536 + 32768 + nf * 8192 + boffr + (c ? cb1 : cb0));
  };

  f32x4 acc[8][4] = {};
  i32x8 alo[4], ahi[4], bloA[2], bloB[2], bhi[2];

  #define RDA4(DST, P, MB)                                                     \
    _Pragma("unroll")                                                          \
    for (int m_ = 0; m_ < 4; ++m_) {                                           \
      i32x4 lo_ = ldA4(P, (MB) + m_, 0), hi_ = ldA4(P, (MB) + m_, 1);          \
      i32x8 r_; r_[0]=lo_[0]; r_[1]=lo_[1]; r_[2]=lo_[2]; r_[3]=lo_[3];        \
      r_[4]=hi_[0]; r_[5]=hi_[1]; r_[6]=hi_[2]; r_[7]=hi_[3]; DST[m_] = r_; }
  #define RDB4(DST, P, NBASE)                                                  \
    _Pragma("unroll")                                                          \
    for (int n_ = 0; n_ < 2; ++n_) {                                           \
      i32x4 lo_ = ldB4(P, (NBASE) + n_, 0), hi_ = ldB4(P, (NBASE) + n_, 1);    \
      i32x8 r_; r_[0]=lo_[0]; r_[1]=lo_[1]; r_[2]=lo_[2]; r_[3]=lo_[3];        \
      r_[4]=hi_[0]; r_[5]=hi_[1]; r_[6]=hi_[2]; r_[7]=hi_[3]; DST[n_] = r_; }
  #define CL8(AF, BF, MO, NO)                                                  \
    __builtin_amdgcn_s_setprio(1);                                             \
    _Pragma("unroll")                                                          \
    for (int m_ = 0; m_ < 4; ++m_)                                             \
      _Pragma("unroll")                                                        \
      for (int n_ = 0; n_ < 2; ++n_)                                           \
        acc[(MO) + m_][(NO) + n_] =                                            \
            __builtin_amdgcn_mfma_scale_f32_16x16x128_f8f6f4(                  \
                AF[m_], BF[n_], acc[(MO) + m_][(NO) + n_],                     \
                0, 0, 0, SCONE, 0, SCONE);                                     \
    __builtin_amdgcn_s_setprio(0);

  stageA(0, 0, 0); stageA(0, 1, 0); stageB(0, 0, 0); stageB(0, 1, 0);
  stageA(1, 0, 1); stageA(1, 1, 1); stageB(1, 0, 1); stageB(1, 1, 1);
  VMC8();
  BAR();
  RDA4(alo, 0, 0);
  RDB4(bloA, 0, 0);

  const int niter = nt >> 1;
  for (int i = 0; i < niter; ++i) {
    const int t2 = 2 * i + 2, t3 = 2 * i + 3;
    LGKM0();
    CL8(alo, bloA, 0, 0);
    RDB4(bhi, 0, 2);
    BAR();
    LGKM0();
    CL8(alo, bhi, 0, 2);
    RDA4(ahi, 0, 4);
    stageB(0, 0, t2);
    VMC2();
    BAR();
    LGKM0();
    CL8(ahi, bhi, 4, 2);
    RDB4(bloB, 1, 0);
    stageB(0, 1, t2); stageA(0, 0, t2);
    BAR();
    LGKM0();
    CL8(ahi, bloA, 4, 0);
    RDA4(alo, 1, 0);
    stageA(0, 1, t2);
    BAR();
    LGKM0();
    CL8(alo, bloB, 0, 0);
    RDB4(bhi, 1, 2);
    BAR();
    LGKM0();
    CL8(alo, bhi, 0, 2);
    RDA4(ahi, 1, 4);
    stageB(1, 0, t3);
    VMC2();
    BAR();
    LGKM0();
    CL8(ahi, bhi, 4, 2);
    RDB4(bloA, 0, 0);
    stageB(1, 1, t3); stageA(1, 0, t3);
    BAR();
    LGKM0();
    CL8(ahi, bloB, 4, 0);
    RDA4(alo, 0, 0);
    stageA(1, 1, t3);
    BAR();
  }
  #undef RDA4
  #undef RDB4
  #undef CL8

  // epilogue: E = exp(sim) bf16 + per-block row-sum partials.
  const int crow0 = brow * 256 + wr * 16 + lhi * 4;
  const int ccol0 = bcol * 256 + wc * 16 + lr;
  float rs[8][4];
  #pragma unroll
  for (int m = 0; m < 8; ++m)
    #pragma unroll
    for (int j = 0; j < 4; ++j) rs[m][j] = 0.f;
  #pragma unroll
  for (int m = 0; m < 8; ++m)
    #pragma unroll
    for (int n = 0; n < 4; ++n)
      #pragma unroll
      for (int j = 0; j < 4; ++j) {
        const float e = __expf(acc[m][n][j]);
        rs[m][j] += e;
        E[(size_t)(crow0 + m * 32 + j) * ldc + ccol0 + n * 64] = f2bf(e);
      }
  #pragma unroll
  for (int m = 0; m < 8; ++m)
    #pragma unroll
    for (int j = 0; j < 4; ++j)
      #pragma unroll
      for (int o = 1; o < 16; o <<= 1) rs[m][j] += __shfl_xor(rs[m][j], o);
  VMC0();            // clamped in-flight stages still write smem
  __syncthreads();
  float* ls = (float*)smem;   // [wc][256 rows] = 4 KiB
  if (lr == 0) {
    #pragma unroll
    for (int m = 0; m < 8; ++m)
      #pragma unroll
      for (int j = 0; j < 4; ++j)
        ls[wc * 256 + wr * 16 + m * 32 + lhi * 4 + j] = rs[m][j];
  }
  __syncthreads();
  if (t < 256) {
    const float s4 = ls[t] + ls[256 + t] + ls[512 + t] + ls[768 + t];
    psum[(size_t)bcol * NB + brow * 256 + t] = s4;
  }
}

// ---- sinv: 1/rowsum from psum[32][NB] --------------------------------------
__global__ void sinv_kernel(const float* __restrict__ psum, float* __restrict__ sinv) {
  const int row = blockIdx.x * 256 + threadIdx.x;
  float s = 0.f;
  #pragma unroll
  for (int k = 0; k < 32; ++k) s += psum[(size_t)k * NB + row];
  sinv[row] = 1.0f / s;
}

// ====== GEMM2: 256x256 bf16, r10 ring, split-K partials + FUSED attn write ==
// part[ksp] = E * memt^T (k-slice); then each block writes its 64-row x
// kchunk slice of attn = bf2f(E)*sinv (E re-read from L2; r11-measured win).
__global__ __launch_bounds__(512, 2) void gemm4r(
    const unsigned short* __restrict__ A, const unsigned short* __restrict__ B,
    float* __restrict__ C, const float* __restrict__ sinvp,
    float* __restrict__ attnp, int ld, int ldc, int mt, int tps, int kchunk,
    unsigned long long cstride)
{
  extern __shared__ char smem[];
  const int t = threadIdx.x;
  const int w = t >> 6, l = t & 63;
  const int wr = w >> 2, wc = w & 3;
  const int nwg = gridDim.x, cpx = nwg >> 3;
  const int id = (blockIdx.x & 7) * cpx + (blockIdx.x >> 3);
  const int ksp = id / tps, rem = id % tps;
  const int brow = rem % mt, bcol = rem / mt;
  const int k0 = ksp * kchunk;
  const int nt = kchunk >> 6;

  const int srow = l >> 3;
  const int scol = ((l & 7) ^ srow) << 3;
  const int lr = l & 15, lhi = l >> 4;
  const int swz = (l & 7) << 4;
  const int cbk0 = (lhi * 16) ^ swz;
  const int cbk1 = (64 + lhi * 16) ^ swz;
  const int aoffr = (wr * 16 + lr) * 128;
  const int boffr = (wc * 16 + lr) * 128;

  const unsigned short* Ab = A + (size_t)(brow * 256 + w * 8 + srow) * ld + k0 + scol;
  const unsigned short* Bb = B + (size_t)(bcol * 256 + w * 8 + srow) * ld + k0 + scol;

  auto stageA = [&](int p, int h, int tau) {
    const int kt = (tau < nt ? tau : nt - 1) << 6;
    const unsigned short* g = Ab + (size_t)(h * 128) * ld + kt;
    char* d = smem + p * 65536 + h * 16384 + w * 1024;
    gload_lds16(g, d);
    gload_lds16(g + (size_t)64 * ld, d + 8192);
  };
  auto stageB = [&](int p, int h, int tau) {
    const int kt = (tau < nt ? tau : nt - 1) << 6;
    const unsigned short* g = Bb + (size_t)(h * 128) * ld + kt;
    char* d = smem + p * 65536 + 32768 + h * 16384 + w * 1024;
    gload_lds16(g, d);
    gload_lds16(g + (size_t)64 * ld, d + 8192);
  };
  auto ldA = [&](int p, int m, int kk) -> bf16x8 {
    return *(const bf16x8*)(smem + p * 65536 + m * 4096 + aoffr + (kk ? cbk1 : cbk0));
  };
  auto ldB = [&](int p, int nf, int kk) -> bf16x8 {
    return *(const bf16x8*)(smem + p * 65536 + 32768 + nf * 8192 + boffr + (kk ? cbk1 : cbk0));
  };

  f32x4 acc[8][4] = {};
  bf16x8 alo[4][2], ahi[4][2], bloA[2][2], bloB[2][2], bhi[2][2];

  stageA(0, 0, 0); stageA(0, 1, 0); stageB(0, 0, 0); stageB(0, 1, 0);
  stageA(1, 0, 1); stageA(1, 1, 1); stageB(1, 0, 1); stageB(1, 1, 1);
  VMC8();
  BAR();
  #pragma unroll
  for (int m = 0; m < 4; ++m) { alo[m][0] = ldA(0, m, 0); alo[m][1] = ldA(0, m, 1); }
  #pragma unroll
  for (int n = 0; n < 2; ++n) { bloA[n][0] = ldB(0, n, 0); bloA[n][1] = ldB(0, n, 1); }

  #define CL(AF, BF, MO, NO)                                                   \
    __builtin_amdgcn_s_setprio(1);                                             \
    _Pragma("unroll")                                                          \
    for (int kk = 0; kk < 2; ++kk)                                             \
      _Pragma("unroll")                                                        \
      for (int m = 0; m < 4; ++m)                                              \
        _Pragma("unroll")                                                      \
        for (int n = 0; n < 2; ++n)                                            \
          acc[MO + m][NO + n] = __builtin_amdgcn_mfma_f32_16x16x32_bf16(       \
              AF[m][kk], BF[n][kk], acc[MO + m][NO + n], 0, 0, 0);             \
    __builtin_amdgcn_s_setprio(0);

  const int niter = nt >> 1;
  for (int i = 0; i < niter; ++i) {
    const int t2 = 2 * i + 2, t3 = 2 * i + 3;
    LGKM0();
    CL(alo, bloA, 0, 0);
    #pragma unroll
    for (int n = 0; n < 2; ++n) { bhi[n][0] = ldB(0, 2 + n, 0); bhi[n][1] = ldB(0, 2 + n, 1); }
    BAR();
    LGKM0();
    CL(alo, bhi, 0, 2);
    #pragma unroll
    for (int m = 0; m < 4; ++m) { ahi[m][0] = ldA(0, 4 + m, 0); ahi[m][1] = ldA(0, 4 + m, 1); }
    stageB(0, 0, t2);
    VMC2();
    BAR();
    LGKM0();
    CL(ahi, bhi, 4, 2);
    #pragma unroll
    for (int n = 0; n < 2; ++n) { bloB[n][0] = ldB(1, n, 0); bloB[n][1] = ldB(1, n, 1); }
    stageB(0, 1, t2); stageA(0, 0, t2);
    BAR();
    LGKM0();
    CL(ahi, bloA, 4, 0);
    #pragma unroll
    for (int m = 0; m < 4; ++m) { alo[m][0] = ldA(1, m, 0); alo[m][1] = ldA(1, m, 1); }
    stageA(0, 1, t2);
    BAR();
    LGKM0();
    CL(alo, bloB, 0, 0);
    #pragma unroll
    for (int n = 0; n < 2; ++n) { bhi[n][0] = ldB(1, 2 + n, 0); bhi[n][1] = ldB(1, 2 + n, 1); }
    BAR();
    LGKM0();
    CL(alo, bhi, 0, 2);
    #pragma unroll
    for (int m = 0; m < 4; ++m) { ahi[m][0] = ldA(1, 4 + m, 0); ahi[m][1] = ldA(1, 4 + m, 1); }
    stageB(1, 0, t3);
    VMC2();
    BAR();
    LGKM0();
    CL(ahi, bhi, 4, 2);
    #pragma unroll
    for (int n = 0; n < 2; ++n) { bloA[n][0] = ldB(0, n, 0); bloA[n][1] = ldB(0, n, 1); }
    stageB(1, 1, t3); stageA(1, 0, t3);
    BAR();
    LGKM0();
    CL(ahi, bloB, 4, 0);
    #pragma unroll
    for (int m = 0; m < 4; ++m) { alo[m][0] = ldA(0, m, 0); alo[m][1] = ldA(0, m, 1); }
    stageA(1, 1, t3);
    BAR();
  }
  #undef CL

  const int crow0 = brow * 256 + wr * 16 + lhi * 4;
  const int ccol0 = bcol * 256 + wc * 16 + lr;
  float* Cp = C + (unsigned long long)ksp * cstride;
  #pragma unroll
  for (int m = 0; m < 8; ++m)
    #pragma unroll
    for (int n = 0; n < 4; ++n)
      #pragma unroll
      for (int j = 0; j < 4; ++j)
        Cp[(size_t)(crow0 + m * 32 + j) * ldc + ccol0 + n * 64] = acc[m][n][j];

  // ---- fused attn write: this block's 64-row x kchunk slice ---------------
  // rows r0..r0+63 where r0 = brow*256 + bcol*64; cols k0..k0+kchunk.
  {
    const int r0 = brow * 256 + bcol * 64;
    const int nch = kchunk >> 3;    // u16x8 chunks per row
    for (int idx = t; idx < 64 * nch; idx += 512) {
      const int row = idx / nch, ch = idx % nch;
      const float inv = sinvp[r0 + row];
      u16x8 bv = *(const u16x8*)(A + (size_t)(r0 + row) * ld + k0 + ch * 8);
      float4 f0, f1;
      #pragma unroll
      for (int j = 0; j < 8; ++j) {
        const float a = bf2f(bv[j]) * inv;
        if (j < 4) (&f0.x)[j] = a; else (&f1.x)[j - 4] = a;
      }
      float* arow = attnp + (size_t)(r0 + row) * NM + k0 + ch * 8;
      *(float4*)arow = f0;
      *(float4*)(arow + 4) = f1;
    }
  }
}

// ---- reduce partials: mf = (sum_k part[k]) * sinv[row], S = 4 --------------
__global__ void reduce_kernel(const float4* __restrict__ part, float4* __restrict__ mf,
                              const float* __restrict__ sinv) {
  const size_t n4 = (size_t)NB * ND / 4;
  for (size_t i = (size_t)blockIdx.x * blockDim.x + threadIdx.x; i < n4;
       i += (size_t)gridDim.x * blockDim.x) {
    const float is = sinv[i >> 8];
    float4 s = part[i];
    #pragma unroll
    for (int k = 1; k < 4; ++k) {
      float4 p = part[(size_t)k * n4 + i];
      s.x += p.x; s.y += p.y; s.z += p.z; s.w += p.w;
    }
    s.x *= is; s.y *= is; s.z *= is; s.w *= is;
    mf[i] = s;
  }
}

extern "C" void kernel_launch(void* const* d_in, const int* in_sizes, int n_in,
                              void* d_out, int out_size, void* d_ws, size_t ws_size,
                              hipStream_t stream) {
  const float* q   = (const float*)d_in[0];
  const float* mem = (const float*)d_in[1];
  float* mf   = (float*)d_out;                       // [4096 x 1024]
  float* attn = (float*)d_out + (size_t)NB * ND;     // [4096 x 8192]
  char* ws = (char*)d_ws;
  uint8_t* memn8       = (uint8_t*)(ws);                               // 8 MiB
  unsigned short* memn = (unsigned short*)(ws + ((size_t)8  << 20));   // 16 MiB
  unsigned short* memt = (unsigned short*)(ws + ((size_t)24 << 20));   // 16 MiB
  unsigned short* E    = (unsigned short*)(ws + ((size_t)40 << 20));   // 64 MiB
  float* psum          = (float*)(ws + ((size_t)104 << 20));           // 512 KiB
  float* sinv          = (float*)(ws + ((size_t)104 << 20) + (512 << 10)); // 16 KiB
  float* part          = (float*)(ws + ((size_t)105 << 20));           // 64 MiB
  uint8_t* qn8         = (uint8_t*)(ws + ((size_t)105 << 20));         // 4 MiB (dead before GEMM2)

  hipFuncSetAttribute((const void*)gemm4x,
                      hipFuncAttributeMaxDynamicSharedMemorySize, 131072);
  hipFuncSetAttribute((const void*)gemm4r,
                      hipFuncAttributeMaxDynamicSharedMemorySize, 131072);

  hipLaunchKernelGGL(nrm_m8, dim3(NM), dim3(256), 0, stream, mem, memn, memn8);
  hipLaunchKernelGGL(nrm_q8, dim3(NB), dim3(256), 0, stream, q, qn8);
  hipLaunchKernelGGL(tr_kernel, dim3(ND / 64, NM / 64), dim3(256), 0, stream, memn, memt);

  // E = exp(qn8 * memn8^T) bf16 + psum : MX-fp8, M=4096, N=8192, K=1024.
  hipLaunchKernelGGL(gemm4x, dim3((NB / 256) * (NM / 256)), dim3(512), 131072, stream,
                     qn8, memn8, E, psum, ND, NM, NB / 256, ND);

  // sinv[row] = 1 / sum_k psum[k][row]
  hipLaunchKernelGGL(sinv_kernel, dim3(NB / 256), dim3(256), 0, stream, psum, sinv);

  // part[k] = E * memt^T (k-slice) + fused attn = E*sinv write (fp32)
  const int tps = (NB / 256) * (ND / 256);   // 64
  hipLaunchKernelGGL(gemm4r, dim3(tps * 4), dim3(512), 131072, stream,
                     E, memt, part, sinv, attn, NM, ND, NB / 256, tps, NM / 4,
                     (unsigned long long)NB * ND);
  hipLaunchKernelGGL(reduce_kernel, dim3(2048), dim3(256), 0, stream,
                     (const float4*)part, (float4*)mf, sinv);
}